// Round 9
// baseline (11181.488 us; speedup 1.0000x reference)
//
#include <hip/hip_runtime.h>

typedef unsigned short u16;
typedef unsigned long long u64;
typedef short bf16x8 __attribute__((ext_vector_type(8)));
typedef float f32x4 __attribute__((ext_vector_type(4)));

#define B_ 256
#define T_ 512
#define I_ 64
#define H_ 512
#define RING 16

// ---------------- ws layout (bytes) ----------------
// Tile: 64 h-cols x 32 rows -> 8 jn x 8 ib = 64 blocks/layer, 128 total (2x CU slack).
// Exchange (A-frag coalesced): [k8=k/8][row 0..255][8 bf16] as u64 pairs per cell.
// Mailboxes: [8 ib][8 jn] lines of 32 u32; 8 producer slots used; 1 block polls its line.
#define OFF_FR0   0u           // 2048 u32 (L0 recurrent ready)
#define OFF_FP    8192u        // 2048 u32 (L0 -> L1 h1 ready)
#define OFF_FR1   16384u       // 2048 u32 (L1 recurrent ready)
#define OFF_FC    24576u       // 2048 u32 (L1 -> L0 ring consumed)
#define OFF_B0    32768u       // 2048 f32
#define OFF_B1    40960u       // 2048 f32
#define OFF_WIH0  49152u       // 2048x64 bf16
#define OFF_WHH0  311296u      // 2048x512 bf16
#define OFF_WIH1  2408448u     // 2048x512 bf16
#define OFF_WHH1  4505600u     // 2048x512 bf16
#define OFF_HX0   6602752u     // 2 x 32768 u64 (L0 exchange)
#define OFF_HX1   7127040u     // 2 x 32768 u64 (L1 exchange)
#define OFF_RING  7651328u     // RING x 32768 u64 (h1 ring)
#define WS_NEEDED 11845632u

#define AQ __ATOMIC_RELAXED
#define SC __HIP_MEMORY_SCOPE_AGENT
#define MFMA_(a, b, c) __builtin_amdgcn_mfma_f32_16x16x32_bf16((a), (b), (c), 0, 0, 0)

static __device__ __forceinline__ u16 f2b(float f) {
  union { float f; unsigned u; } v; v.f = f;
  unsigned r = (v.u + 0x7FFFu + ((v.u >> 16) & 1u)) >> 16;
  return (u16)r;
}
static __device__ __forceinline__ float sigm(float x) { return 1.f / (1.f + __expf(-x)); }
static __device__ __forceinline__ float tanh_(float x) { return 1.f - 2.f / (__expf(2.f * x) + 1.f); }

// A-frag load from exchange (u64 view of [k8][256][8 bf16]): 16B coalesced per lane.
static __device__ __forceinline__ bf16x8 ld_afrag(const u64* base, int k8, int row) {
  const u64* p = base + ((size_t)k8 * 256 + row) * 2;
  union { u64 q[2]; bf16x8 v; } u;
  u.q[0] = __hip_atomic_load(p, AQ, SC);
  u.q[1] = __hip_atomic_load(p + 1, AQ, SC);
  return u.v;
}

// ---------------- prep: bf16 weights, bias sums, flag zero, out=bfc ----------------
__global__ void prep_kernel(const float* __restrict__ Wih0, const float* __restrict__ Whh0,
                            const float* __restrict__ bih0, const float* __restrict__ bhh0,
                            const float* __restrict__ Wih1, const float* __restrict__ Whh1,
                            const float* __restrict__ bih1, const float* __restrict__ bhh1,
                            const float* __restrict__ bfc, float* __restrict__ out,
                            char* __restrict__ ws) {
  unsigned* flags = (unsigned*)(ws + OFF_FR0);  // FR0..FC contiguous: 8192 u32
  float* b0 = (float*)(ws + OFF_B0);
  float* b1 = (float*)(ws + OFF_B1);
  u16* wih0b = (u16*)(ws + OFF_WIH0);
  u16* whh0b = (u16*)(ws + OFF_WHH0);
  u16* wih1b = (u16*)(ws + OFF_WIH1);
  u16* whh1b = (u16*)(ws + OFF_WHH1);

  long long i = (long long)blockIdx.x * 256 + threadIdx.x;
  if (i < 8192) { __hip_atomic_store(&flags[i], 0u, AQ, SC); return; }
  i -= 8192;
  if (i < 256) { out[i] = bfc[0]; return; }   // FC bias; L1 atomicAdds partials
  i -= 256;
  if (i < 2048) { b0[i] = bih0[i] + bhh0[i]; return; }
  i -= 2048;
  if (i < 2048) { b1[i] = bih1[i] + bhh1[i]; return; }
  i -= 2048;
  if (i < 131072) { wih0b[i] = f2b(Wih0[i]); return; }
  i -= 131072;
  if (i < 1048576) { whh0b[i] = f2b(Whh0[i]); return; }
  i -= 1048576;
  if (i < 1048576) { wih1b[i] = f2b(Wih1[i]); return; }
  i -= 1048576;
  if (i < 1048576) { whh1b[i] = f2b(Whh1[i]); return; }
}

// ---------------- fused 2-layer pipelined LSTM ----------------
// 128 blocks, 1/CU (LDS-limited), 2x CU slack: blocks 0-63 = L0, 64-127 = L1 (lag 1).
// Per layer: jn = bx&7 (64 h-cols), ib = bx>>3 (32 batch rows).
// 4 waves K-split K=512 (4 ksteps each); B-fragments streamed from L2 each step.
template <bool IS_L0>
__device__ __forceinline__ void lstm_body(
    int bx,
    const float* __restrict__ x,      // L0: [B,T,64]
    const u16* __restrict__ Wib,      // bf16: L0 [2048][64], L1 [2048][512]
    const u16* __restrict__ Whb,      // bf16 [2048][512]
    const float* __restrict__ bias,   // [2048]
    u64* __restrict__ hxq,            // own exchange [2][32768] u64
    u64* __restrict__ ringq,          // ring [RING][32768] u64
    const float* __restrict__ Wfc, float* __restrict__ out,
    unsigned* __restrict__ fOwn,      // own recurrent mailbox (poll + write)
    unsigned* __restrict__ fP,        // h1-ready (L0 writes, L1 polls)
    unsigned* __restrict__ fC,        // ring-consumed (L1 writes, L0 polls)
    float* __restrict__ Gp_s, u16* __restrict__ Ax_s)
{
  const int tid = threadIdx.x;
  const int wv = tid >> 6;
  const int lane = tid & 63;
  const int quad = lane >> 4;
  const int l15 = lane & 15;
  const int jn = bx & 7;
  const int ib = bx >> 3;
  const int erow = tid & 31;   // elementwise: batch row within block
  const int oct = tid >> 5;    // elementwise: col octet (cols jn*64 + oct*8 + j)
  const unsigned lineoff = ((unsigned)ib * 8 + jn) * 32;

  float bias8[4][8];
#pragma unroll
  for (int g = 0; g < 4; ++g)
#pragma unroll
    for (int j = 0; j < 8; ++j)
      bias8[g][j] = bias[g * 512 + jn * 64 + oct * 8 + j];
  float c8[8] = {0.f, 0.f, 0.f, 0.f, 0.f, 0.f, 0.f, 0.f};
  const f32x4 zf = {0.f, 0.f, 0.f, 0.f};

  if constexpr (IS_L0) {  // prologue: stage x(0)
    int row = tid >> 3, cc = (tid & 7) * 8;
    const float* xp = x + ((size_t)(ib * 32 + row) * T_) * 64 + cc;
    float4 a = *(const float4*)xp;
    float4 b = *(const float4*)(xp + 4);
    uint4 v;
    v.x = (unsigned)f2b(a.x) | ((unsigned)f2b(a.y) << 16);
    v.y = (unsigned)f2b(a.z) | ((unsigned)f2b(a.w) << 16);
    v.z = (unsigned)f2b(b.x) | ((unsigned)f2b(b.y) << 16);
    v.w = (unsigned)f2b(b.z) | ((unsigned)f2b(b.w) << 16);
    *(uint4*)&Ax_s[row * 72 + cc] = v;
    __syncthreads();
  }

  for (int t = 0; t < T_; ++t) {
    f32x4 acc[2][16];
#pragma unroll
    for (int mt = 0; mt < 2; ++mt)
#pragma unroll
      for (int nt = 0; nt < 16; ++nt) acc[mt][nt] = zf;

    if constexpr (IS_L0) {
      // input GEMM (h-independent, before poll); x staged previous step
      if (wv < 2) {
        const int kk = wv * 32 + quad * 8;
        bf16x8 a0 = *(const bf16x8*)&Ax_s[l15 * 72 + kk];
        bf16x8 a1 = *(const bf16x8*)&Ax_s[(16 + l15) * 72 + kk];
#pragma unroll
        for (int nt = 0; nt < 16; ++nt) {
          bf16x8 b0 = *(const bf16x8*)&Wib[(size_t)((nt >> 2) * 512 + jn * 64 + (nt & 3) * 16 + l15) * 64 + kk];
          acc[0][nt] = MFMA_(a0, b0, acc[0][nt]);
          acc[1][nt] = MFMA_(a1, b0, acc[1][nt]);
        }
      }
      // poll (all waves): recurrent ready + ring back-pressure
      if (t) {
        const unsigned tgtR = (unsigned)t;
        const unsigned tgtC = (t >= RING) ? (unsigned)(t - RING + 1) : 0u;
        for (;;) {
          unsigned vv = 1u, tg = 0u;
          if (lane < 8) { vv = __hip_atomic_load(&fOwn[lineoff + lane], AQ, SC); tg = tgtR; }
          else if (lane >= 32 && lane < 40) { vv = __hip_atomic_load(&fC[lineoff + (lane - 32)], AQ, SC); tg = tgtC; }
          if (!__any(vv < tg)) break;
        }
      }
      // recurrent GEMM: A from exchange, B streamed from L2
      if (t) {
        const u64* hq = hxq + (size_t)(t & 1) * 32768;
        bf16x8 af[4][2];
#pragma unroll
        for (int r = 0; r < 4; ++r) {
          int k8 = wv * 16 + r * 4 + quad;
          af[r][0] = ld_afrag(hq, k8, ib * 32 + l15);
          af[r][1] = ld_afrag(hq, k8, ib * 32 + 16 + l15);
        }
#pragma unroll
        for (int r = 0; r < 4; ++r) {
          const int kc = (wv * 4 + r) * 32 + quad * 8;
#pragma unroll
          for (int nt = 0; nt < 16; ++nt) {
            bf16x8 bh = *(const bf16x8*)&Whb[(size_t)((nt >> 2) * 512 + jn * 64 + (nt & 3) * 16 + l15) * 512 + kc];
            acc[0][nt] = MFMA_(af[r][0], bh, acc[0][nt]);
            acc[1][nt] = MFMA_(af[r][1], bh, acc[1][nt]);
          }
        }
      }
    } else {
      // poll (all waves): h1(t) ready + own recurrent ready
      {
        const unsigned tgtP = (unsigned)(t + 1);
        const unsigned tgtR = (unsigned)t;
        for (;;) {
          unsigned vv = 1u, tg = 0u;
          if (lane < 8) { vv = __hip_atomic_load(&fP[lineoff + lane], AQ, SC); tg = tgtP; }
          else if (lane >= 32 && lane < 40) { vv = __hip_atomic_load(&fOwn[lineoff + (lane - 32)], AQ, SC); tg = tgtR; }
          if (!__any(vv < tg)) break;
        }
      }
      // input GEMM from h1 ring
      {
        const u64* rq = ringq + (size_t)(t & (RING - 1)) * 32768;
        bf16x8 af[4][2];
#pragma unroll
        for (int r = 0; r < 4; ++r) {
          int k8 = wv * 16 + r * 4 + quad;
          af[r][0] = ld_afrag(rq, k8, ib * 32 + l15);
          af[r][1] = ld_afrag(rq, k8, ib * 32 + 16 + l15);
        }
#pragma unroll
        for (int r = 0; r < 4; ++r) {
          const int kc = (wv * 4 + r) * 32 + quad * 8;
#pragma unroll
          for (int nt = 0; nt < 16; ++nt) {
            bf16x8 bx = *(const bf16x8*)&Wib[(size_t)((nt >> 2) * 512 + jn * 64 + (nt & 3) * 16 + l15) * 512 + kc];
            acc[0][nt] = MFMA_(af[r][0], bx, acc[0][nt]);
            acc[1][nt] = MFMA_(af[r][1], bx, acc[1][nt]);
          }
        }
      }
      // recurrent GEMM
      if (t) {
        const u64* hq = hxq + (size_t)(t & 1) * 32768;
        bf16x8 af[4][2];
#pragma unroll
        for (int r = 0; r < 4; ++r) {
          int k8 = wv * 16 + r * 4 + quad;
          af[r][0] = ld_afrag(hq, k8, ib * 32 + l15);
          af[r][1] = ld_afrag(hq, k8, ib * 32 + 16 + l15);
        }
#pragma unroll
        for (int r = 0; r < 4; ++r) {
          const int kc = (wv * 4 + r) * 32 + quad * 8;
#pragma unroll
          for (int nt = 0; nt < 16; ++nt) {
            bf16x8 bh = *(const bf16x8*)&Whb[(size_t)((nt >> 2) * 512 + jn * 64 + (nt & 3) * 16 + l15) * 512 + kc];
            acc[0][nt] = MFMA_(af[r][0], bh, acc[0][nt]);
            acc[1][nt] = MFMA_(af[r][1], bh, acc[1][nt]);
          }
        }
      }
    }

    // ---- dump per-wave partials (D: col=l15, row=quad*4+reg); stride 262 -> 2-way=free
#pragma unroll
    for (int mt = 0; mt < 2; ++mt)
#pragma unroll
      for (int nt = 0; nt < 16; ++nt)
#pragma unroll
        for (int rr = 0; rr < 4; ++rr)
          Gp_s[(wv * 32 + mt * 16 + quad * 4 + rr) * 262 + nt * 16 + l15] = acc[mt][nt][rr];
    __syncthreads();  // A

    // ---- elementwise: reduce 4 wave-partials, gates, c/h (8 cols x 1 row / thread)
    {
      float pre[4][8];
#pragma unroll
      for (int g = 0; g < 4; ++g)
#pragma unroll
        for (int p = 0; p < 4; ++p) {
          float s0 = bias8[g][2 * p], s1 = bias8[g][2 * p + 1];
#pragma unroll
          for (int w = 0; w < 4; ++w) {
            const float2 v = *(const float2*)&Gp_s[(w * 32 + erow) * 262 + g * 64 + oct * 8 + 2 * p];
            s0 += v.x; s1 += v.y;
          }
          pre[g][2 * p] = s0; pre[g][2 * p + 1] = s1;
        }
      float hv[8];
#pragma unroll
      for (int j = 0; j < 8; ++j) {
        float iv = sigm(pre[0][j]);
        float fv = sigm(pre[1][j]);
        float gv = tanh_(pre[2][j]);
        float ov = sigm(pre[3][j]);
        float cn = fv * c8[j] + iv * gv;
        c8[j] = cn;
        hv[j] = ov * tanh_(cn);
      }
      u64 lo = (u64)f2b(hv[0]) | ((u64)f2b(hv[1]) << 16) | ((u64)f2b(hv[2]) << 32) | ((u64)f2b(hv[3]) << 48);
      u64 hi = (u64)f2b(hv[4]) | ((u64)f2b(hv[5]) << 16) | ((u64)f2b(hv[6]) << 32) | ((u64)f2b(hv[7]) << 48);
      const size_t cell = ((size_t)(jn * 8 + oct) * 256 + ib * 32 + erow) * 2;
      const size_t pb = (size_t)((t + 1) & 1) * 32768;
      __hip_atomic_store(&hxq[pb + cell], lo, AQ, SC);      // write-through
      __hip_atomic_store(&hxq[pb + cell + 1], hi, AQ, SC);
      if constexpr (IS_L0) {
        const size_t rb = (size_t)(t & (RING - 1)) * 32768;
        __hip_atomic_store(&ringq[rb + cell], lo, AQ, SC);
        __hip_atomic_store(&ringq[rb + cell + 1], hi, AQ, SC);
      } else if (t == T_ - 1) {
        float part = 0.f;
#pragma unroll
        for (int j = 0; j < 8; ++j) part += hv[j] * Wfc[jn * 64 + oct * 8 + j];
        part += __shfl_down(part, 32);  // pair lanes share erow (octs 2wv, 2wv+1)
        if (lane < 32) atomicAdd(&out[ib * 32 + erow], part);
      }
    }

    if constexpr (IS_L0) {
      if (t + 1 < T_) {  // stage x(t+1): step-t readers all passed syncA
        int row = tid >> 3, cc = (tid & 7) * 8;
        const float* xp = x + ((size_t)(ib * 32 + row) * T_ + t + 1) * 64 + cc;
        float4 a = *(const float4*)xp;
        float4 b = *(const float4*)(xp + 4);
        uint4 v;
        v.x = (unsigned)f2b(a.x) | ((unsigned)f2b(a.y) << 16);
        v.y = (unsigned)f2b(a.z) | ((unsigned)f2b(a.w) << 16);
        v.z = (unsigned)f2b(b.x) | ((unsigned)f2b(b.y) << 16);
        v.w = (unsigned)f2b(b.z) | ((unsigned)f2b(b.w) << 16);
        *(uint4*)&Ax_s[row * 72 + cc] = v;
      }
    }
    __syncthreads();  // B: drains all waves' h stores (vmcnt(0) before s_barrier)

    // ---- signal: wave0 scatters flags to the 8 consumers of each mailbox
    if (wv == 0) {
      const unsigned val = (unsigned)(t + 1);
      if (lane < 8) {
        if (t + 1 < T_)
          __hip_atomic_store(&fOwn[((unsigned)ib * 8 + lane) * 32 + jn], val, AQ, SC);
      } else if (lane >= 32 && lane < 40) {
        if constexpr (IS_L0) {
          __hip_atomic_store(&fP[((unsigned)ib * 8 + (lane - 32)) * 32 + jn], val, AQ, SC);
        } else {
          if (t + 1 < T_)
            __hip_atomic_store(&fC[((unsigned)ib * 8 + (lane - 32)) * 32 + jn], val, AQ, SC);
        }
      }
    }
  }
}

__global__ __launch_bounds__(256, 1) void lstm_fused(
    const float* __restrict__ x,
    const u16* __restrict__ wih0, const u16* __restrict__ whh0, const float* __restrict__ b0,
    const u16* __restrict__ wih1, const u16* __restrict__ whh1, const float* __restrict__ b1,
    u64* __restrict__ hx0, u64* __restrict__ hx1, u64* __restrict__ ringq,
    const float* __restrict__ Wfc, float* __restrict__ out,
    unsigned* __restrict__ fR0, unsigned* __restrict__ fP, unsigned* __restrict__ fR1,
    unsigned* __restrict__ fC)
{
  __shared__ __align__(16) float Gp_s[128 * 262];   // 134144 B
  __shared__ __align__(16) u16 Ax_s[32 * 72];       // 4608 B
  if (blockIdx.x < 64)
    lstm_body<true>(blockIdx.x, x, wih0, whh0, b0, hx0, ringq,
                    (const float*)nullptr, (float*)nullptr, fR0, fP, fC, Gp_s, Ax_s);
  else
    lstm_body<false>(blockIdx.x - 64, (const float*)nullptr, wih1, whh1, b1, hx1, ringq,
                     Wfc, out, fR1, fP, fC, Gp_s, Ax_s);
}

extern "C" void kernel_launch(void* const* d_in, const int* in_sizes, int n_in,
                              void* d_out, int out_size, void* d_ws, size_t ws_size,
                              hipStream_t stream) {
  if (ws_size < (size_t)WS_NEEDED) return;

  const float* x    = (const float*)d_in[0];
  const float* Wih0 = (const float*)d_in[1];
  const float* Whh0 = (const float*)d_in[2];
  const float* bih0 = (const float*)d_in[3];
  const float* bhh0 = (const float*)d_in[4];
  const float* Wih1 = (const float*)d_in[5];
  const float* Whh1 = (const float*)d_in[6];
  const float* bih1 = (const float*)d_in[7];
  const float* bhh1 = (const float*)d_in[8];
  const float* Wfc  = (const float*)d_in[9];
  const float* bfc  = (const float*)d_in[10];

  char* ws = (char*)d_ws;
  unsigned* fR0  = (unsigned*)(ws + OFF_FR0);
  unsigned* fP   = (unsigned*)(ws + OFF_FP);
  unsigned* fR1  = (unsigned*)(ws + OFF_FR1);
  unsigned* fC   = (unsigned*)(ws + OFF_FC);
  float* b0      = (float*)(ws + OFF_B0);
  float* b1      = (float*)(ws + OFF_B1);
  u16* wih0b     = (u16*)(ws + OFF_WIH0);
  u16* whh0b     = (u16*)(ws + OFF_WHH0);
  u16* wih1b     = (u16*)(ws + OFF_WIH1);
  u16* whh1b     = (u16*)(ws + OFF_WHH1);
  u64* hx0       = (u64*)(ws + OFF_HX0);
  u64* hx1       = (u64*)(ws + OFF_HX1);
  u64* ringq     = (u64*)(ws + OFF_RING);
  float* out     = (float*)d_out;

  // prep: 8192 + 256 + 2048*2 + 131072 + 3*1048576 = 3,289,344 = 12849 x 256
  prep_kernel<<<12849, 256, 0, stream>>>(Wih0, Whh0, bih0, bhh0, Wih1, Whh1, bih1, bhh1,
                                         bfc, out, ws);

  lstm_fused<<<128, 256, 0, stream>>>(x, wih0b, whh0b, b0, wih1b, whh1b, b1,
                                      hx0, hx1, ringq, Wfc, out, fR0, fP, fR1, fC);
}